// Round 7
// baseline (338.025 us; speedup 1.0000x reference)
//
#include <hip/hip_runtime.h>

// SchroederReverb: 4 series allpass (N=225,556,441,341, g=0.7) then 4 parallel
// feedback combs (N=1116,1188,1277,1356, g=.84,.82,.80,.78) summed.
//
// Verified closed form (rounds 3-5): the allpass chain is the identity plus a
// zero-head transient; composing all 4 stages:
//     s[n] = x[n] - pw[n/225]*x[n%225] - pw[n/556]*h1[n%556],
// pw[m] = (-0.7)^m (inline exp2f), h1[m] head rows [0,556):
//     h1[m<225]=0; h1[225<=m<450]=x[m]+0.7x[m-225]; h1[m>=450]=x[m]-0.49x[m-450].
//
// Round-13: REVERT round-6's two regressions (fp16 s: combs 59us vs <39.7,
// absmax 0.125; prep fused into comb1: 60.5us, gathers+exp2f killed scan BW).
// Back to round-5's fp32 materialized-s (227us, all stages <39.7us).
// ONE change: comb geometry 512thr/S=8/grid=1024 -> 256thr/S=4/grid=items.
//   Round-5 combs had items(1116-1356) > processors(1024 resident blocks)
//   -> ceil=2 scheduling rounds, round 2 at 9-33% occupancy (+5-8us/comb).
//   256-thr blocks: 5-6 resident/CU (arg2 = min BLOCKS/CU, verified round-7)
//   = 1280-1536 processors >= items -> ONE fully-occupied round per comb.
// VGPR: L doubles (25-30), y[L]*2 = 50-60 + xs/addr ~ 72-82.
//   c1/c2/c3 arg2=5 (20 waves/CU -> cap 102); c4 arg2=6 (cap 85, est 72).
// Coverage (S=4): S*L >= Kmax, (S-1)*L <= Kmin:
//   c1 N=1116 K=118/117 L=30 (120,90)   c2 N=1188 K=111/110 L=28 (112,84)
//   c3 N=1277 K=103/102 L=26 (104,78)   c4 N=1356 K= 97/ 96 L=25 (100,75)
// comb1 writes out, combs 2-4 RMW. NO atomics (2.2 TB/s, prior session).
//
// Comb semantics (identical to passing rounds 1-12):
//   y[k=0]=0; y[k] = g*y[k-1] + s[k]   per chain (k>=1)

constexpr int W = 128;

template <int V> struct fv { float d[V]; };

template <int V>
__device__ __forceinline__ fv<V> fv_zero() {
  fv<V> r;
#pragma unroll
  for (int c = 0; c < V; ++c) r.d[c] = 0.f;
  return r;
}
using fv2 = fv<2>;
using fv4 = fv<4>;

// ---- march: y[k] = a*y[k-1] + s[n], s preloaded; n is a ROW index ---------
template <int K, bool PRED>
__device__ __forceinline__
void fmarch_blk(const fv2* __restrict__ sb, int n0, int N, int lane,
                int Tn, float a, fv2& yp, fv2* __restrict__ y) {
  fv2 xs[K];
#pragma unroll
  for (int u = 0; u < K; ++u) {
    const int n = n0 + u * N;
    xs[u] = (!PRED || n < Tn) ? sb[n * 64 + lane] : fv_zero<2>();
  }
#pragma unroll
  for (int u = 0; u < K; ++u) {
#pragma unroll
    for (int c = 0; c < 2; ++c)
      yp.d[c] = fmaf(a, yp.d[c], xs[u].d[c]);
    y[u] = yp;
  }
}

template <int CNT, bool PRED, int U>
__device__ __forceinline__
void fmarch_seg(const fv2* __restrict__ sb, int n0, int N, int lane,
                int Tn, float a, fv2& yp, fv2* __restrict__ y) {
  constexpr int NB = CNT / U, R = CNT % U;
#pragma unroll
  for (int b = 0; b < NB; ++b)
    fmarch_blk<U, PRED>(sb, n0 + b * U * N, N, lane, Tn, a, yp, y + b * U);
  if constexpr (R > 0)
    fmarch_blk<R, PRED>(sb, n0 + NB * U * N, N, lane, Tn, a, yp, y + NB * U);
}

// ---- store pass: y_true[j] = y[j] + a^(j+1)*Yin  (MODE 2: += out) ---------
template <int MODE, int K, bool PRED>
__device__ __forceinline__
void fstore_blk(fv2* __restrict__ out, int n0, int N, int lane, int Tn,
                float a, fv2 Yin, const fv2* __restrict__ y, float& p) {
  fv2 os[K];
  if constexpr (MODE == 2) {
#pragma unroll
    for (int u = 0; u < K; ++u) {
      const int n = n0 + u * N;
      os[u] = (!PRED || n < Tn) ? out[n * 64 + lane] : fv_zero<2>();
    }
  }
#pragma unroll
  for (int u = 0; u < K; ++u) {
    const int n = n0 + u * N;
    fv2 v;
#pragma unroll
    for (int c = 0; c < 2; ++c) {
      v.d[c] = fmaf(p, Yin.d[c], y[u].d[c]);
      if constexpr (MODE == 2) v.d[c] += os[u].d[c];
    }
    if (!PRED || n < Tn) out[n * 64 + lane] = v;
    p *= a;
  }
}

template <int MODE, int CNT, bool PRED, int U>
__device__ __forceinline__
void fstore_seg(fv2* __restrict__ out, int n0, int N, int lane, int Tn,
                float a, fv2 Yin, const fv2* __restrict__ y, float p0) {
  constexpr int NB = CNT / U, R = CNT % U;
  float p = p0;
#pragma unroll
  for (int b = 0; b < NB; ++b)
    fstore_blk<MODE, U, PRED>(out, n0 + b * U * N, N, lane, Tn, a, Yin,
                              y + b * U, p);
  if constexpr (R > 0)
    fstore_blk<MODE, R, PRED>(out, n0 + NB * U * N, N, lane, Tn, a, Yin,
                              y + NB * U, p);
}

// ---- comb stage: single-chain items, wave = one 512B row -------------------
// Item = chain r; grid = items (<= resident capacity -> one balanced round).
// S waves/block; LDS carries; affine store fixup; two syncthreads per item.
// MINB: __launch_bounds__ arg2 = min BLOCKS/CU (verified round-7 semantics).
template <int MODE, int S, int L, int MINB, int UM, int US>
__global__ __launch_bounds__(S * 64, MINB)
void fcomb(const fv2* __restrict__ sb, fv2* __restrict__ out,
           int N, float g, float aL, int T, int items) {
  const float a = g;
  __shared__ fv2 C[S][64];
  const int tid = threadIdx.x;
  const int s  = tid >> 6;                  // segment (wave-uniform)
  const int l6 = tid & 63;                  // lane = fv2 column within row

  for (int item = blockIdx.x; item < items; item += gridDim.x) {
    const int r  = item;
    const int n0 = s * L * N + r;

    fv2 y[L];
    fv2 yp = fv_zero<2>();

    if (s == 0) {
      y[0] = fv_zero<2>();                  // y[k=0] forced to 0
      fmarch_seg<L - 1, false, UM>(sb, n0 + N, N, l6, T, a, yp, y + 1);
    } else if (s < S - 1) {
      fmarch_seg<L, false, UM>(sb, n0, N, l6, T, a, yp, y);
    } else {
      fmarch_seg<L, true, UM>(sb, n0, N, l6, T, a, yp, y);
    }
    C[s][l6] = yp;
    __syncthreads();

    // fold incoming state: Yin = sum_{j<s} aL^(s-1-j) * C[j]
    fv2 Yin = fv_zero<2>();
    for (int j = 0; j < s; ++j) {
#pragma unroll
      for (int c = 0; c < 2; ++c)
        Yin.d[c] = fmaf(aL, Yin.d[c], C[j][l6].d[c]);
    }
    __syncthreads();                        // C reusable by next item

    if (s < S - 1)
      fstore_seg<MODE, L, false, US>(out, n0, N, l6, T, a, Yin, y, a);
    else
      fstore_seg<MODE, L, true, US>(out, n0, N, l6, T, a, Yin, y, a);
  }
}

// ---- single prep kernel: s[n] = x[n] - pw1[q1]*x[r1] - pw2[q2]*h1(r2) ------
// pw inline via exp2f (|err| ~1e-4 rel, tol 0.0625); h1 inline from x rows
// (both gathers hit the first 556 rows of x -> L2/L3-resident).
__global__ __launch_bounds__(1024)
void prep_s(const fv4* __restrict__ x, fv4* __restrict__ sb) {
  const int e = blockIdx.x * 1024 + threadIdx.x;  // over T*32 fv4 elems
  const int n  = e >> 5;
  const int lo = e & 31;
  const int q1 = n / 225, r1 = n - q1 * 225;      // compile-time magic-mul
  const int q2 = n / 556, r2 = n - q2 * 556;
  const float LG = -0.5145731728297583f;          // log2(0.7)
  const float m1 = exp2f((float)q1 * LG);
  const float m2 = exp2f((float)q2 * LG);
  const float p1 = (q1 & 1) ? -m1 : m1;           // (-0.7)^q1
  const float p2 = (q2 & 1) ? -m2 : m2;           // (-0.7)^q2

  const fv4 xs = x[e];
  const fv4 t1 = x[r1 * 32 + lo];
  fv4 t2;
  if (r2 < 225) {
    t2 = fv_zero<4>();
  } else {
    t2 = x[r2 * 32 + lo];
    const int   d = (r2 < 450) ? 225 : 450;
    const float c = (r2 < 450) ? 0.7f : -0.49f;   // -(-0.7)^1 / -(-0.7)^2
    const fv4 tt = x[(r2 - d) * 32 + lo];
#pragma unroll
    for (int k = 0; k < 4; ++k) t2.d[k] = fmaf(c, tt.d[k], t2.d[k]);
  }
  fv4 v;
#pragma unroll
  for (int k = 0; k < 4; ++k) {
    float sv = fmaf(-p1, t1.d[k], xs.d[k]);
    v.d[k] = fmaf(-p2, t2.d[k], sv);
  }
  sb[e] = v;
}

// ---- generic fallback (any T): original full recurrence pipeline -----------
constexpr int W2 = 64;
template <int MODE, bool STORE>
__device__ __forceinline__
void g_march(const float2* __restrict__ in, float2* __restrict__ out,
             int n, int N, int cnt, int T, int lane, float g, float a,
             float2& xp, float2& yp) {
  for (int j = 0; j < cnt; ++j) {
    float2 x = (n < T) ? in[n * W2 + lane] : make_float2(0.f, 0.f);
    float ux = (MODE == 0) ? fmaf(g, xp.x, x.x) : x.x;
    float uy = (MODE == 0) ? fmaf(g, xp.y, x.y) : x.y;
    yp.x = fmaf(a, yp.x, ux);
    yp.y = fmaf(a, yp.y, uy);
    xp = x;
    if (STORE && n < T) {
      float2 v = yp;
      if (MODE == 2) { v.x += out[n * W2 + lane].x; v.y += out[n * W2 + lane].y; }
      out[n * W2 + lane] = v;
    }
    n += N;
  }
}

template <int MODE>
__global__ __launch_bounds__(1024)
void stage_gen(const float2* __restrict__ in, float2* __restrict__ out,
               int N, float g, float aL, int L, int T) {
  const float a = (MODE == 0) ? -g : g;
  __shared__ float2 C[16][W2];
  const int tid = threadIdx.x, s = tid >> 6, lane = tid & 63;
  const int r = blockIdx.x;
  if (r >= T) return;
  const int n0 = s * L * N + r;
  if (s == 0) {
    float2 xp = make_float2(0.f, 0.f), yp = make_float2(0.f, 0.f);
    if (MODE == 0) xp = in[r * W2 + lane];
    if (MODE != 2) out[r * W2 + lane] = make_float2(0.f, 0.f);
    g_march<MODE, true>(in, out, r + N, N, L - 1, T, lane, g, a, xp, yp);
    C[0][lane] = yp;
    __syncthreads();
    return;
  }
  {
    float2 xp = make_float2(0.f, 0.f), yp = make_float2(0.f, 0.f);
    if (MODE == 0) xp = in[(n0 - N) * W2 + lane];
    g_march<MODE, false>(in, out, n0, N, L, T, lane, g, a, xp, yp);
    C[s][lane] = yp;
  }
  __syncthreads();
  float2 Yin = make_float2(0.f, 0.f);
  for (int j = 0; j < s; ++j) {
    Yin.x = fmaf(aL, Yin.x, C[j][lane].x);
    Yin.y = fmaf(aL, Yin.y, C[j][lane].y);
  }
  float2 xp = make_float2(0.f, 0.f), yp = Yin;
  if (MODE == 0) xp = in[(n0 - N) * W2 + lane];
  g_march<MODE, true>(in, out, n0, N, L, T, lane, g, a, xp, yp);
}

// ---- host ------------------------------------------------------------------
static void pick_SL(int T, int N, int S0, int* Sp, int* Lp) {
  int Kmin = T / N, Kmax = (T + N - 1) / N;
  int S = S0;
  for (; S > 1; --S) {
    int L = (Kmax + S - 1) / S;
    if ((S - 1) * L <= Kmin) break;
  }
  *Sp = S;
  *Lp = (Kmax + *Sp - 1) / *Sp;
}

static float pow_f(float a, int n) {
  double p = 1.0;
  for (int i = 0; i < n; ++i) p *= (double)a;
  return (float)p;
}

extern "C" void kernel_launch(void* const* d_in, const int* in_sizes, int n_in,
                              void* d_out, int out_size, void* d_ws, size_t ws_size,
                              hipStream_t stream) {
  float* out = (float*)d_out;
  float* ws  = (float*)d_ws;
  const float* x = (const float*)d_in[0];
  const int T = in_sizes[0] / W;          // 131072

  if (T == 131072) {
    float* sbf = ws;                      // s buffer: T*W floats (64 MiB)

    // T*32 fv4 elems = 4,194,304 = 4096 * 1024 exactly
    hipLaunchKernelGGL(prep_s, dim3(4096), dim3(1024), 0, stream,
                       (const fv4*)x, (fv4*)sbf);

    const fv2* s2 = (const fv2*)sbf;
    fv2* o2 = (fv2*)out;

    // 256-thr blocks (S=4), grid = items -> one balanced scheduling round.
    // comb1 N=1116 (K=118): L=30, arg2=5 (write)
    hipLaunchKernelGGL((fcomb<1, 4, 30, 5, 4, 4>), dim3(1116), dim3(256),
                       0, stream, s2, o2, 1116, 0.84f, pow_f(0.84f, 30), T, 1116);
    // comb2 N=1188 (K=111): L=28, arg2=5 (RMW)
    hipLaunchKernelGGL((fcomb<2, 4, 28, 5, 4, 4>), dim3(1188), dim3(256),
                       0, stream, s2, o2, 1188, 0.82f, pow_f(0.82f, 28), T, 1188);
    // comb3 N=1277 (K=103): L=26, arg2=5 (RMW)
    hipLaunchKernelGGL((fcomb<2, 4, 26, 5, 4, 4>), dim3(1277), dim3(256),
                       0, stream, s2, o2, 1277, 0.80f, pow_f(0.80f, 26), T, 1277);
    // comb4 N=1356 (K=97): L=25, arg2=6 (RMW)
    hipLaunchKernelGGL((fcomb<2, 4, 25, 6, 4, 4>), dim3(1356), dim3(256),
                       0, stream, s2, o2, 1356, 0.78f, pow_f(0.78f, 25), T, 1356);
  } else {
    const int   apN[4] = {225, 556, 441, 341};
    const int   cbN[4] = {1116, 1188, 1277, 1356};
    const float cbG[4] = {0.84f, 0.82f, 0.80f, 0.78f};
    const float2* src = (const float2*)x;
    float2* bufs[2] = {(float2*)out, (float2*)ws};
    int cur = 0;
    for (int i = 0; i < 4; ++i) {
      int S, L;
      pick_SL(T, apN[i], 16, &S, &L);
      hipLaunchKernelGGL((stage_gen<0>), dim3(apN[i]), dim3(S * 64), 0, stream,
                         src, bufs[cur], apN[i], 0.7f, pow_f(-0.7f, L), L, T);
      src = bufs[cur];
      cur ^= 1;
    }
    float2* dst = (src == (float2*)out) ? (float2*)ws : (float2*)out;
    for (int i = 0; i < 4; ++i) {
      int S, L;
      pick_SL(T, cbN[i], 16, &S, &L);
      if (i == 0)
        hipLaunchKernelGGL((stage_gen<1>), dim3(cbN[i]), dim3(S * 64), 0, stream,
                           src, dst, cbN[i], cbG[i], pow_f(cbG[i], L), L, T);
      else
        hipLaunchKernelGGL((stage_gen<2>), dim3(cbN[i]), dim3(S * 64), 0, stream,
                           src, dst, cbN[i], cbG[i], pow_f(cbG[i], L), L, T);
    }
    if (dst != (float2*)out)
      hipMemcpyAsync(out, dst, (size_t)T * W * sizeof(float),
                     hipMemcpyDeviceToDevice, stream);
  }
}

// Round 8
// 227.332 us; speedup vs baseline: 1.4869x; 1.4869x over previous
//
#include <hip/hip_runtime.h>

// SchroederReverb: 4 series allpass (N=225,556,441,341, g=0.7) then 4 parallel
// feedback combs (N=1116,1188,1277,1356, g=.84,.82,.80,.78) summed.
//
// Verified closed form (rounds 3-5): the allpass chain is the identity plus a
// zero-head transient; composing all 4 stages:
//     s[n] = x[n] - pw[n/225]*x[n%225] - pw[n/556]*h1[n%556],
// pw[m] = (-0.7)^m (inline exp2f), h1[m] head rows [0,556):
//     h1[m<225]=0; h1[225<=m<450]=x[m]+0.7x[m-225]; h1[m>=450]=x[m]-0.49x[m-450].
//
// Round-14: revert round-13 (arg2=5 forced the 8-waves/EU step -> 64-VGPR cap
// -> y[] spilled, VGPR=48, WRITE 2x, 338us). Occupancy steps are COARSE
// (waves/EU halve at VGPR 64/128/256); only request proven points:
// (512 thr, arg2=2) -> cap 128, observed safe rounds 2-4.
// Base = round-5 skeleton (227us, best verified). ONE change: s stored FP16
// with WIDE loads. Round-6 proved fp16 s is tolerance-safe (passed, 0.125)
// but its 4B/lane loads ran 2.8 TB/s; here lanes load 4 halves (8B) with the
// round-4 pair-item geometry (wave = 2 chains, 1 KiB per 2 rows, y[] fv4).
// Same load-instruction count per byte as round-5 fp32 combs, half the bytes:
// traffic 871 -> 703 MB.
// Combs keep the proven segmented scan: S=8 waves/block, LDS carries, affine
// store fixup y_true[j] = y[j] + a^(j+1)*Yin, item loop, grid 512,
// comb1 writes out, combs 2-4 RMW, comb3 ODDN guard (r=1277 invalid).
// NO atomics (2.2 TB/s, prior session).
//
// Comb semantics (identical to passing rounds 1-13):
//   y[k=0]=0; y[k] = g*y[k-1] + s[k]   per chain (k>=1)
//
// Coverage (S=8, verified round-4): S*L >= Kmax, (S-1)*L <= Kmin:
//   c1 N=1116 K=118/117 L=15   c2 N=1188 K=111/110 L=14
//   c3 N=1277 K=103/102 L=13   c4 N=1356 K= 97/ 96 L=13

constexpr int W = 128;

template <int V> struct fv { float d[V]; };

template <int V>
__device__ __forceinline__ fv<V> fv_zero() {
  fv<V> r;
#pragma unroll
  for (int c = 0; c < V; ++c) r.d[c] = 0.f;
  return r;
}
using fv2 = fv<2>;
using fv4 = fv<4>;

struct h4 { _Float16 d[4]; };               // 4 fp16 (8 B)

// ---- march: y[k] = a*y[k-1] + s[n], s fp16 preloaded 8B/lane --------------
template <int K, bool PRED>
__device__ __forceinline__
void fmarch_blk(const h4* __restrict__ sb, int n0, int N, int lo,
                int Tn, float a, fv4& yp, fv4* __restrict__ y) {
  h4 xs[K];
#pragma unroll
  for (int u = 0; u < K; ++u) {
    const int n = n0 + u * N;
    if (!PRED || n < Tn) {
      xs[u] = sb[n * 32 + lo];
    } else {
#pragma unroll
      for (int c = 0; c < 4; ++c) xs[u].d[c] = (_Float16)0.f;
    }
  }
#pragma unroll
  for (int u = 0; u < K; ++u) {
#pragma unroll
    for (int c = 0; c < 4; ++c)
      yp.d[c] = fmaf(a, yp.d[c], (float)xs[u].d[c]);
    y[u] = yp;
  }
}

template <int CNT, bool PRED, int U>
__device__ __forceinline__
void fmarch_seg(const h4* __restrict__ sb, int n0, int N, int lo,
                int Tn, float a, fv4& yp, fv4* __restrict__ y) {
  constexpr int NB = CNT / U, R = CNT % U;
#pragma unroll
  for (int b = 0; b < NB; ++b)
    fmarch_blk<U, PRED>(sb, n0 + b * U * N, N, lo, Tn, a, yp, y + b * U);
  if constexpr (R > 0)
    fmarch_blk<R, PRED>(sb, n0 + NB * U * N, N, lo, Tn, a, yp, y + NB * U);
}

// ---- store pass: y_true[j] = y[j] + a^(j+1)*Yin  (MODE 2: += out) ---------
template <int MODE, int K, bool PRED>
__device__ __forceinline__
void fstore_blk(fv4* __restrict__ out, int n0, int N, int lo, int Tn,
                float a, fv4 Yin, const fv4* __restrict__ y, float& p) {
  fv4 os[K];
  if constexpr (MODE == 2) {
#pragma unroll
    for (int u = 0; u < K; ++u) {
      const int n = n0 + u * N;
      os[u] = (!PRED || n < Tn) ? out[n * 32 + lo] : fv_zero<4>();
    }
  }
#pragma unroll
  for (int u = 0; u < K; ++u) {
    const int n = n0 + u * N;
    fv4 v;
#pragma unroll
    for (int c = 0; c < 4; ++c) {
      v.d[c] = fmaf(p, Yin.d[c], y[u].d[c]);
      if constexpr (MODE == 2) v.d[c] += os[u].d[c];
    }
    if (!PRED || n < Tn) out[n * 32 + lo] = v;
    p *= a;
  }
}

template <int MODE, int CNT, bool PRED, int U>
__device__ __forceinline__
void fstore_seg(fv4* __restrict__ out, int n0, int N, int lo, int Tn,
                float a, fv4 Yin, const fv4* __restrict__ y, float p0) {
  constexpr int NB = CNT / U, R = CNT % U;
  float p = p0;
#pragma unroll
  for (int b = 0; b < NB; ++b)
    fstore_blk<MODE, U, PRED>(out, n0 + b * U * N, N, lo, Tn, a, Yin,
                              y + b * U, p);
  if constexpr (R > 0)
    fstore_blk<MODE, R, PRED>(out, n0 + NB * U * N, N, lo, Tn, a, Yin,
                              y + NB * U, p);
}

// ---- comb stage: pair items, lane = 4 fp16 cols of one chain ---------------
// Item = chain pair (r = 2*item + (l6>>5)); wave = 2 rows, 1 KiB s-granule.
// Grid 512 = resident capacity at 2 blocks/CU (launch_bounds(512,2) -> cap
// 128, VERIFIED safe). Two syncthreads per item. ODDN: r==N invalid -> Tn=0.
template <int MODE, int S, int L, bool ODDN, int UM, int US>
__global__ __launch_bounds__(S * 64, 2)
void fcomb(const h4* __restrict__ sb, fv4* __restrict__ out,
           int N, float g, float aL, int T, int items) {
  const float a = g;
  __shared__ fv4 C[S][64];
  const int tid = threadIdx.x;
  const int s  = tid >> 6;                  // segment (wave-uniform)
  const int l6 = tid & 63;
  const int lo = l6 & 31;                   // h4 column within row

  for (int item = blockIdx.x; item < items; item += gridDim.x) {
    const int r  = (item << 1) | (l6 >> 5); // 2 chains per wave
    const int Tn = (!ODDN || r < N) ? T : 0;
    const int n0 = s * L * N + r;

    fv4 y[L];
    fv4 yp = fv_zero<4>();

    if (s == 0) {
      y[0] = fv_zero<4>();                  // y[k=0] forced to 0
      fmarch_seg<L - 1, ODDN, UM>(sb, n0 + N, N, lo, Tn, a, yp, y + 1);
    } else if (!ODDN && s < S - 1) {
      fmarch_seg<L, false, UM>(sb, n0, N, lo, Tn, a, yp, y);
    } else {
      fmarch_seg<L, true, UM>(sb, n0, N, lo, Tn, a, yp, y);
    }
    C[s][l6] = yp;
    __syncthreads();

    // fold incoming state: Yin = sum_{j<s} aL^(s-1-j) * C[j]
    fv4 Yin = fv_zero<4>();
    for (int j = 0; j < s; ++j) {
#pragma unroll
      for (int c = 0; c < 4; ++c)
        Yin.d[c] = fmaf(aL, Yin.d[c], C[j][l6].d[c]);
    }
    __syncthreads();                        // C reusable by next item

    if (!ODDN && s < S - 1)
      fstore_seg<MODE, L, false, US>(out, n0, N, lo, Tn, a, Yin, y, a);
    else
      fstore_seg<MODE, L, true, US>(out, n0, N, lo, Tn, a, Yin, y, a);
  }
}

// ---- single prep kernel: s[n] = x[n] - pw1[q1]*x[r1] - pw2[q2]*h1(r2) ------
// pw inline via exp2f (|err| ~1e-4 rel); h1 inline from x rows (first 556
// rows of x -> L2/L3-resident). Output fp16 (8B/thread store, contiguous).
__global__ __launch_bounds__(1024)
void prep_s(const fv4* __restrict__ x, h4* __restrict__ sb) {
  const int e = blockIdx.x * 1024 + threadIdx.x;  // over T*32 units
  const int n  = e >> 5;
  const int lo = e & 31;
  const int q1 = n / 225, r1 = n - q1 * 225;      // compile-time magic-mul
  const int q2 = n / 556, r2 = n - q2 * 556;
  const float LG = -0.5145731728297583f;          // log2(0.7)
  const float m1 = exp2f((float)q1 * LG);
  const float m2 = exp2f((float)q2 * LG);
  const float p1 = (q1 & 1) ? -m1 : m1;           // (-0.7)^q1
  const float p2 = (q2 & 1) ? -m2 : m2;           // (-0.7)^q2

  const fv4 xs = x[e];
  const fv4 t1 = x[r1 * 32 + lo];
  fv4 t2;
  if (r2 < 225) {
    t2 = fv_zero<4>();
  } else {
    t2 = x[r2 * 32 + lo];
    const int   d = (r2 < 450) ? 225 : 450;
    const float c = (r2 < 450) ? 0.7f : -0.49f;   // -(-0.7)^1 / -(-0.7)^2
    const fv4 tt = x[(r2 - d) * 32 + lo];
#pragma unroll
    for (int k = 0; k < 4; ++k) t2.d[k] = fmaf(c, tt.d[k], t2.d[k]);
  }
  h4 v;
#pragma unroll
  for (int k = 0; k < 4; ++k) {
    float sv = fmaf(-p1, t1.d[k], xs.d[k]);
    v.d[k] = (_Float16)fmaf(-p2, t2.d[k], sv);
  }
  sb[e] = v;
}

// ---- generic fallback (any T): original full recurrence pipeline -----------
constexpr int W2 = 64;
template <int MODE, bool STORE>
__device__ __forceinline__
void g_march(const float2* __restrict__ in, float2* __restrict__ out,
             int n, int N, int cnt, int T, int lane, float g, float a,
             float2& xp, float2& yp) {
  for (int j = 0; j < cnt; ++j) {
    float2 x = (n < T) ? in[n * W2 + lane] : make_float2(0.f, 0.f);
    float ux = (MODE == 0) ? fmaf(g, xp.x, x.x) : x.x;
    float uy = (MODE == 0) ? fmaf(g, xp.y, x.y) : x.y;
    yp.x = fmaf(a, yp.x, ux);
    yp.y = fmaf(a, yp.y, uy);
    xp = x;
    if (STORE && n < T) {
      float2 v = yp;
      if (MODE == 2) { v.x += out[n * W2 + lane].x; v.y += out[n * W2 + lane].y; }
      out[n * W2 + lane] = v;
    }
    n += N;
  }
}

template <int MODE>
__global__ __launch_bounds__(1024)
void stage_gen(const float2* __restrict__ in, float2* __restrict__ out,
               int N, float g, float aL, int L, int T) {
  const float a = (MODE == 0) ? -g : g;
  __shared__ float2 C[16][W2];
  const int tid = threadIdx.x, s = tid >> 6, lane = tid & 63;
  const int r = blockIdx.x;
  if (r >= T) return;
  const int n0 = s * L * N + r;
  if (s == 0) {
    float2 xp = make_float2(0.f, 0.f), yp = make_float2(0.f, 0.f);
    if (MODE == 0) xp = in[r * W2 + lane];
    if (MODE != 2) out[r * W2 + lane] = make_float2(0.f, 0.f);
    g_march<MODE, true>(in, out, r + N, N, L - 1, T, lane, g, a, xp, yp);
    C[0][lane] = yp;
    __syncthreads();
    return;
  }
  {
    float2 xp = make_float2(0.f, 0.f), yp = make_float2(0.f, 0.f);
    if (MODE == 0) xp = in[(n0 - N) * W2 + lane];
    g_march<MODE, false>(in, out, n0, N, L, T, lane, g, a, xp, yp);
    C[s][lane] = yp;
  }
  __syncthreads();
  float2 Yin = make_float2(0.f, 0.f);
  for (int j = 0; j < s; ++j) {
    Yin.x = fmaf(aL, Yin.x, C[j][lane].x);
    Yin.y = fmaf(aL, Yin.y, C[j][lane].y);
  }
  float2 xp = make_float2(0.f, 0.f), yp = Yin;
  if (MODE == 0) xp = in[(n0 - N) * W2 + lane];
  g_march<MODE, true>(in, out, n0, N, L, T, lane, g, a, xp, yp);
}

// ---- host ------------------------------------------------------------------
static void pick_SL(int T, int N, int S0, int* Sp, int* Lp) {
  int Kmin = T / N, Kmax = (T + N - 1) / N;
  int S = S0;
  for (; S > 1; --S) {
    int L = (Kmax + S - 1) / S;
    if ((S - 1) * L <= Kmin) break;
  }
  *Sp = S;
  *Lp = (Kmax + *Sp - 1) / *Sp;
}

static float pow_f(float a, int n) {
  double p = 1.0;
  for (int i = 0; i < n; ++i) p *= (double)a;
  return (float)p;
}

extern "C" void kernel_launch(void* const* d_in, const int* in_sizes, int n_in,
                              void* d_out, int out_size, void* d_ws, size_t ws_size,
                              hipStream_t stream) {
  float* out = (float*)d_out;
  float* ws  = (float*)d_ws;
  const float* x = (const float*)d_in[0];
  const int T = in_sizes[0] / W;          // 131072

  if (T == 131072) {
    h4* sb16 = (h4*)ws;                   // fp16 s buffer: T*32 h4 = 32 MiB

    // T*32 units = 4,194,304 = 4096 * 1024 exactly
    hipLaunchKernelGGL(prep_s, dim3(4096), dim3(1024), 0, stream,
                       (const fv4*)x, sb16);

    const h4* s16 = (const h4*)sb16;
    fv4* o4 = (fv4*)out;

    // Pair items; grid 512 (= resident capacity at 2 blocks/CU, cap 128).
    // comb1 N=1116 (K=118): L=15, items=558 (write)
    hipLaunchKernelGGL((fcomb<1, 8, 15, false, 4, 4>), dim3(512), dim3(512),
                       0, stream, s16, o4, 1116, 0.84f, pow_f(0.84f, 15), T, 558);
    // comb2 N=1188 (K=111): L=14, items=594 (RMW)
    hipLaunchKernelGGL((fcomb<2, 8, 14, false, 4, 4>), dim3(512), dim3(512),
                       0, stream, s16, o4, 1188, 0.82f, pow_f(0.82f, 14), T, 594);
    // comb3 N=1277 odd (K=103): L=13, items=639 (RMW, ODDN: r=1277 invalid)
    hipLaunchKernelGGL((fcomb<2, 8, 13, true, 4, 4>), dim3(512), dim3(512),
                       0, stream, s16, o4, 1277, 0.80f, pow_f(0.80f, 13), T, 639);
    // comb4 N=1356 (K=97): L=13, items=678 (RMW)
    hipLaunchKernelGGL((fcomb<2, 8, 13, false, 4, 4>), dim3(512), dim3(512),
                       0, stream, s16, o4, 1356, 0.78f, pow_f(0.78f, 13), T, 678);
  } else {
    const int   apN[4] = {225, 556, 441, 341};
    const int   cbN[4] = {1116, 1188, 1277, 1356};
    const float cbG[4] = {0.84f, 0.82f, 0.80f, 0.78f};
    const float2* src = (const float2*)x;
    float2* bufs[2] = {(float2*)out, (float2*)ws};
    int cur = 0;
    for (int i = 0; i < 4; ++i) {
      int S, L;
      pick_SL(T, apN[i], 16, &S, &L);
      hipLaunchKernelGGL((stage_gen<0>), dim3(apN[i]), dim3(S * 64), 0, stream,
                         src, bufs[cur], apN[i], 0.7f, pow_f(-0.7f, L), L, T);
      src = bufs[cur];
      cur ^= 1;
    }
    float2* dst = (src == (float2*)out) ? (float2*)ws : (float2*)out;
    for (int i = 0; i < 4; ++i) {
      int S, L;
      pick_SL(T, cbN[i], 16, &S, &L);
      if (i == 0)
        hipLaunchKernelGGL((stage_gen<1>), dim3(cbN[i]), dim3(S * 64), 0, stream,
                           src, dst, cbN[i], cbG[i], pow_f(cbG[i], L), L, T);
      else
        hipLaunchKernelGGL((stage_gen<2>), dim3(cbN[i]), dim3(S * 64), 0, stream,
                           src, dst, cbN[i], cbG[i], pow_f(cbG[i], L), L, T);
    }
    if (dst != (float2*)out)
      hipMemcpyAsync(out, dst, (size_t)T * W * sizeof(float),
                     hipMemcpyDeviceToDevice, stream);
  }
}